// Round 1
// baseline (1000.801 us; speedup 1.0000x reference)
//
#include <hip/hip_runtime.h>
#include <hip/hip_bf16.h>
#include <math.h>

// Problem constants (b=1, n=768)
#define NRES 768
#define NH 12
#define DQKV 1152
#define PAIRD 128
#define SCD 384
#define DOUTF 2112

#define SS_C 0.14433756729740643f   // (3*16)^-0.5
#define PS_C 0.13608276348795434f   // (3*4*4.5)^-0.5
#define PBS_C 0.5773502691896258f   // 3^-0.5

typedef __attribute__((ext_vector_type(4))) float f32x4;
typedef __attribute__((ext_vector_type(8))) short s16x8;

__device__ __forceinline__ unsigned short f2bf(float x) {
  union { float f; unsigned u; } v; v.f = x;
  unsigned r = (v.u + 0x7fffu + ((v.u >> 16) & 1u)) >> 16;
  return (unsigned short)r;
}

// ---------------- generic fp32 GEMM: C[M,N] = A[M,K]@B[K,N] (+bias) --------
// M,N multiples of 64; K multiple of 16.
__global__ __launch_bounds__(256) void gemm_f32(
    const float* __restrict__ A, const float* __restrict__ B,
    const float* __restrict__ bias, float* __restrict__ C,
    int M, int Nn, int K)
{
  __shared__ __align__(16) float As[16][68];
  __shared__ __align__(16) float Bs[16][68];
  int t = threadIdx.x;
  int m0 = blockIdx.y * 64, n0 = blockIdx.x * 64;
  int tx = t & 15, ty = t >> 4;
  float acc[4][4] = {};
  int am = t >> 2, ak = (t & 3) * 4;
  int bk = t >> 4, bn = (t & 15) * 4;
  for (int k0 = 0; k0 < K; k0 += 16) {
    float4 a4 = *(const float4*)(A + (size_t)(m0 + am) * K + k0 + ak);
    As[ak + 0][am] = a4.x; As[ak + 1][am] = a4.y;
    As[ak + 2][am] = a4.z; As[ak + 3][am] = a4.w;
    float4 b4 = *(const float4*)(B + (size_t)(k0 + bk) * Nn + n0 + bn);
    *(float4*)&Bs[bk][bn] = b4;
    __syncthreads();
#pragma unroll
    for (int k = 0; k < 16; ++k) {
      float4 av = *(float4*)&As[k][ty * 4];
      float4 bv = *(float4*)&Bs[k][tx * 4];
      float ar[4] = {av.x, av.y, av.z, av.w};
      float br[4] = {bv.x, bv.y, bv.z, bv.w};
#pragma unroll
      for (int r = 0; r < 4; ++r)
#pragma unroll
        for (int c = 0; c < 4; ++c)
          acc[r][c] += ar[r] * br[c];
    }
    __syncthreads();
  }
#pragma unroll
  for (int r = 0; r < 4; ++r) {
    int m = m0 + ty * 4 + r;
#pragma unroll
    for (int c = 0; c < 4; ++c) {
      int n = n0 + tx * 4 + c;
      float v = acc[r][c];
      if (bias) v += bias[n];
      C[(size_t)m * Nn + n] = v;
    }
  }
}

// ---------------- point transforms: local -> global frame ------------------
__global__ __launch_bounds__(192) void points_kernel(
    const float* __restrict__ qkv, const float* __restrict__ rot,
    const float* __restrict__ trans, float* __restrict__ QP,
    float* __restrict__ KP, float* __restrict__ VP)
{
  int i = blockIdx.x;
  int t = threadIdx.x;
  const float* R = rot + (size_t)i * 9;
  const float* T = trans + (size_t)i * 3;
  int base; float* outp;
  if (t < 48) { int h = t >> 2, d = t & 3; base = 576 + (h * 4 + d) * 3;
    outp = QP + ((size_t)h * NRES + i) * 12 + d * 3; }
  else if (t < 96) { int u = t - 48; int h = u >> 2, d = u & 3; base = 720 + (h * 4 + d) * 3;
    outp = KP + ((size_t)h * NRES + i) * 12 + d * 3; }
  else { int u = t - 96; int h = u >> 3, d = u & 7; base = 864 + (h * 8 + d) * 3;
    outp = VP + ((size_t)h * NRES + i) * 24 + d * 3; }
  const float* p = qkv + (size_t)i * DQKV + base;
  float p0 = p[0], p1 = p[1], p2 = p[2];
#pragma unroll
  for (int x = 0; x < 3; ++x)
    outp[x] = R[x * 3 + 0] * p0 + R[x * 3 + 1] * p1 + R[x * 3 + 2] * p2 + T[x];
}

// ---------------- Vt: [h][48][768] bf16, rows 0..15 = vs, 16..39 = vp, 40..47 = 0
__global__ __launch_bounds__(256) void vt_kernel(
    const float* __restrict__ qkv, const float* __restrict__ VP,
    unsigned short* __restrict__ Vt)
{
  int b = blockIdx.x;          // 12*48
  int h = b / 48, o = b % 48;
  int t = threadIdx.x;
  for (int p = 0; p < 3; ++p) {
    int j = p * 256 + t;
    float v;
    if (o < 16) v = qkv[(size_t)j * DQKV + 384 + h * 16 + o];
    else if (o < 40) v = VP[((size_t)h * NRES + j) * 24 + (o - 16)];
    else v = 0.f;
    Vt[((size_t)h * 48 + o) * NRES + j] = f2bf(v);
  }
}

// ---------------- scalar + point logits (fp32) -----------------------------
__global__ __launch_bounds__(256) void logits_sp_kernel(
    const float* __restrict__ qkv, const float* __restrict__ QP,
    const float* __restrict__ KP, const float* __restrict__ pw,
    float* __restrict__ Ls, float* __restrict__ Lp)
{
  int jt = blockIdx.x, it = blockIdx.y, h = blockIdx.z;
  int t = threadIdx.x;
  int j = jt * 64 + (t & 63);
  int ig = t >> 6;
  float spw = log1pf(expf(pw[h]));
  float ks[16], kp[12];
  const float* kq = qkv + (size_t)j * DQKV + 192 + h * 16;
#pragma unroll
  for (int d = 0; d < 16; ++d) ks[d] = kq[d];
  const float* kpp = KP + ((size_t)h * NRES + j) * 12;
#pragma unroll
  for (int d = 0; d < 12; ++d) kp[d] = kpp[d];
  for (int ii = 0; ii < 8; ++ii) {
    int i = it * 32 + ig * 8 + ii;
    const float* qq = qkv + (size_t)i * DQKV + h * 16;   // wave-uniform
    const float* qp = QP + ((size_t)h * NRES + i) * 12;
    float s = 0.f, p = 0.f;
#pragma unroll
    for (int d = 0; d < 16; ++d) s += qq[d] * ks[d];
#pragma unroll
    for (int d = 0; d < 12; ++d) p += qp[d] * kp[d];
    size_t off = ((size_t)h * NRES + i) * NRES + j;
    Ls[off] = s;
    Lp[off] = p * spw;
  }
}

// ---------------- pair_bias via MFMA: Lb[h][i][j] = pair[i,j,:]@Wpb[:,h] ---
__global__ __launch_bounds__(256) void pair_bias_kernel(
    const float* __restrict__ pair, const float* __restrict__ Wpb,
    float* __restrict__ Lb)
{
  __shared__ __align__(16) unsigned short Bt[64][136];  // pair tile bf16 [j][d]
  int jt = blockIdx.x, i = blockIdx.y;
  int j0 = jt * 64;
  int t = threadIdx.x;
  int lane = t & 63, w = t >> 6;
  int n15 = lane & 15, q = lane >> 4;
  // B-frags (Wpb, k=d, n=h padded to 16) - block invariant
  s16x8 wf[4];
#pragma unroll
  for (int ks = 0; ks < 4; ++ks) {
#pragma unroll
    for (int jj = 0; jj < 8; ++jj) {
      int k = ks * 32 + q * 8 + jj;
      float v = (n15 < 12) ? Wpb[k * 12 + n15] : 0.f;
      wf[ks][jj] = (short)f2bf(v);
    }
  }
  // stage pair tile -> bf16 LDS
  {
    int dq = t & 31, jb = t >> 5;
    for (int p = 0; p < 8; ++p) {
      int j = p * 8 + jb;
      float4 v = *(const float4*)(pair + ((size_t)i * NRES + j0 + j) * PAIRD + dq * 4);
      unsigned lo = (unsigned)f2bf(v.x) | ((unsigned)f2bf(v.y) << 16);
      unsigned hi = (unsigned)f2bf(v.z) | ((unsigned)f2bf(v.w) << 16);
      uint2 pk; pk.x = lo; pk.y = hi;
      *(uint2*)&Bt[j][dq * 4] = pk;
    }
  }
  __syncthreads();
  f32x4 acc = {0.f, 0.f, 0.f, 0.f};
  int m = w * 16 + n15;
#pragma unroll
  for (int ks = 0; ks < 4; ++ks) {
    s16x8 af = *(const s16x8*)&Bt[m][ks * 32 + q * 8];
    acc = __builtin_amdgcn_mfma_f32_16x16x32_bf16(af, wf[ks], acc, 0, 0, 0);
  }
  if (n15 < 12) {
    int j = j0 + w * 16 + q * 4;     // 4 acc regs = 4 consecutive j
    float4 st; st.x = acc[0]; st.y = acc[1]; st.z = acc[2]; st.w = acc[3];
    *(float4*)(Lb + ((size_t)n15 * NRES + i) * NRES + j) = st;
  }
}

// ---------------- triple softmax (in place), row-per-block -----------------
__global__ __launch_bounds__(256) void softmax_kernel(
    float* __restrict__ Ls, float* __restrict__ Lp, float* __restrict__ Lb)
{
  int i = blockIdx.x, h = blockIdx.y;
  int t = threadIdx.x;
  size_t off = ((size_t)h * NRES + i) * NRES;
  float s[3], p[3], b[3], c[3];
#pragma unroll
  for (int e = 0; e < 3; ++e) {
    int j = t + e * 256;
    s[e] = Ls[off + j];
    p[e] = Lp[off + j];
    b[e] = Lb[off + j];
    c[e] = SS_C * s[e] + PS_C * p[e] + PBS_C * b[e];
  }
  __shared__ float redmax[4][3];
  __shared__ float redsum[4][3];
  float ms = fmaxf(fmaxf(s[0], s[1]), s[2]);
  float mp = fmaxf(fmaxf(p[0], p[1]), p[2]);
  float mc = fmaxf(fmaxf(c[0], c[1]), c[2]);
#pragma unroll
  for (int o = 32; o > 0; o >>= 1) {
    ms = fmaxf(ms, __shfl_down(ms, o));
    mp = fmaxf(mp, __shfl_down(mp, o));
    mc = fmaxf(mc, __shfl_down(mc, o));
  }
  int wv = t >> 6;
  if ((t & 63) == 0) { redmax[wv][0] = ms; redmax[wv][1] = mp; redmax[wv][2] = mc; }
  __syncthreads();
  ms = fmaxf(fmaxf(redmax[0][0], redmax[1][0]), fmaxf(redmax[2][0], redmax[3][0]));
  mp = fmaxf(fmaxf(redmax[0][1], redmax[1][1]), fmaxf(redmax[2][1], redmax[3][1]));
  mc = fmaxf(fmaxf(redmax[0][2], redmax[1][2]), fmaxf(redmax[2][2], redmax[3][2]));
  float es[3], ep[3], ec[3];
  float sums = 0.f, sump = 0.f, sumc = 0.f;
#pragma unroll
  for (int e = 0; e < 3; ++e) {
    es[e] = expf(s[e] - ms); sums += es[e];
    ep[e] = expf(p[e] - mp); sump += ep[e];
    ec[e] = expf(c[e] - mc); sumc += ec[e];
  }
#pragma unroll
  for (int o = 32; o > 0; o >>= 1) {
    sums += __shfl_down(sums, o);
    sump += __shfl_down(sump, o);
    sumc += __shfl_down(sumc, o);
  }
  if ((t & 63) == 0) { redsum[wv][0] = sums; redsum[wv][1] = sump; redsum[wv][2] = sumc; }
  __syncthreads();
  sums = redsum[0][0] + redsum[1][0] + redsum[2][0] + redsum[3][0];
  sump = redsum[0][1] + redsum[1][1] + redsum[2][1] + redsum[3][1];
  sumc = redsum[0][2] + redsum[1][2] + redsum[2][2] + redsum[3][2];
  float rs = 1.f / sums, rp = 1.f / sump, rc = 1.f / sumc;
#pragma unroll
  for (int e = 0; e < 3; ++e) {
    int j = t + e * 256;
    Ls[off + j] = es[e] * rs;   // softmax(scalar_logits)
    Lp[off + j] = ep[e] * rp;   // softmax(point_logits)
    Lb[off + j] = ec[e] * rc;   // attn
  }
}

// ---------------- res_scalar + res_pts: attn[h] @ Vt[h]^T (MFMA) ----------
__global__ __launch_bounds__(192) void res_sv_kernel(
    const float* __restrict__ attn, const unsigned short* __restrict__ Vt,
    float* __restrict__ res_sv)
{
  __shared__ __align__(16) unsigned short A_lds[16][72];
  __shared__ __align__(16) unsigned short B_lds[48][72];
  int it = blockIdx.x, h = blockIdx.y;
  int i0 = it * 16;
  int t = threadIdx.x;
  int lane = t & 63, w = t >> 6;     // wave = n-tile (0..2)
  int n15 = lane & 15, q = lane >> 4;
  f32x4 acc = {0.f, 0.f, 0.f, 0.f};
  for (int jt = 0; jt < 12; ++jt) {
    int j0 = jt * 64;
    __syncthreads();
    for (int idx = t; idx < 1024; idx += 192) {
      int r = idx >> 6, j = idx & 63;
      A_lds[r][j] = f2bf(attn[((size_t)h * NRES + i0 + r) * NRES + j0 + j]);
    }
    for (int idx = t; idx < 1536; idx += 192) {
      int o = idx >> 5, j2 = idx & 31;
      *(unsigned*)&B_lds[o][j2 * 2] =
          *(const unsigned*)&Vt[((size_t)h * 48 + o) * NRES + j0 + j2 * 2];
    }
    __syncthreads();
#pragma unroll
    for (int ks = 0; ks < 2; ++ks) {
      s16x8 af = *(const s16x8*)&A_lds[n15][ks * 32 + q * 8];
      s16x8 bf = *(const s16x8*)&B_lds[w * 16 + n15][ks * 32 + q * 8];
      acc = __builtin_amdgcn_mfma_f32_16x16x32_bf16(af, bf, acc, 0, 0, 0);
    }
  }
  int o = w * 16 + n15;
  if (o < 40) {
#pragma unroll
    for (int r = 0; r < 4; ++r) {
      int i = i0 + q * 4 + r;
      res_sv[((size_t)h * NRES + i) * 40 + o] = acc[r];
    }
  }
}

// ---------------- res_pair: per i, attn(12x768) @ pair[i](768x128) MFMA ----
__global__ __launch_bounds__(256) void res_pair_kernel(
    const float* __restrict__ attn, const float* __restrict__ pair,
    float* __restrict__ res_pair)
{
  __shared__ __align__(16) unsigned short A_lds[16][72];
  __shared__ __align__(16) unsigned short B_lds[64][132];
  int i = blockIdx.x;
  int t = threadIdx.x;
  int lane = t & 63, w = t >> 6;
  int n15 = lane & 15, q = lane >> 4;
  for (int idx = t; idx < 4 * 72; idx += 256)
    A_lds[12 + idx / 72][idx % 72] = 0;     // zero pad rows h=12..15
  f32x4 acc[2];
  acc[0] = (f32x4){0.f, 0.f, 0.f, 0.f};
  acc[1] = (f32x4){0.f, 0.f, 0.f, 0.f};
  for (int jt = 0; jt < 12; ++jt) {
    int j0 = jt * 64;
    __syncthreads();
    for (int idx = t; idx < 768; idx += 256) {
      int r = idx >> 6, j = idx & 63;
      A_lds[r][j] = f2bf(attn[((size_t)r * NRES + i) * NRES + j0 + j]);
    }
    {
      int oq = t & 31, jb = t >> 5;
      for (int p = 0; p < 8; ++p) {
        int j = p * 8 + jb;
        float4 v = *(const float4*)(pair + ((size_t)i * NRES + j0 + j) * PAIRD + oq * 4);
        unsigned lo = (unsigned)f2bf(v.x) | ((unsigned)f2bf(v.y) << 16);
        unsigned hi = (unsigned)f2bf(v.z) | ((unsigned)f2bf(v.w) << 16);
        uint2 pk; pk.x = lo; pk.y = hi;
        *(uint2*)&B_lds[j][oq * 4] = pk;
      }
    }
    __syncthreads();
#pragma unroll
    for (int ks = 0; ks < 2; ++ks) {
      s16x8 af = *(const s16x8*)&A_lds[n15][ks * 32 + q * 8];
#pragma unroll
      for (int nt = 0; nt < 2; ++nt) {
        int o = (w * 2 + nt) * 16 + n15;
        s16x8 bf;
#pragma unroll
        for (int jj = 0; jj < 8; ++jj)
          bf[jj] = (short)B_lds[ks * 32 + q * 8 + jj][o];
        acc[nt] = __builtin_amdgcn_mfma_f32_16x16x32_bf16(af, bf, acc[nt], 0, 0, 0);
      }
    }
  }
#pragma unroll
  for (int nt = 0; nt < 2; ++nt) {
    int o = (w * 2 + nt) * 16 + n15;
#pragma unroll
    for (int r = 0; r < 4; ++r) {
      int hh = q * 4 + r;
      if (hh < 12)
        res_pair[((size_t)hh * NRES + i) * PAIRD + o] = acc[nt][r];
    }
  }
}

// ---------------- feats assembly (+ inverse rigid + norms) -----------------
__global__ __launch_bounds__(256) void feats_kernel(
    const float* __restrict__ res_sv, const float* __restrict__ res_pair,
    const float* __restrict__ rot, const float* __restrict__ trans,
    float* __restrict__ feats)
{
  int i = blockIdx.x;
  int t = threadIdx.x;
  float* F = feats + (size_t)i * DOUTF;
  if (t < 192) {
    int h = t >> 4, d = t & 15;
    F[t] = res_sv[((size_t)h * NRES + i) * 40 + d];
  }
  for (int e = 0; e < 6; ++e) {
    int idx = e * 256 + t;
    int h = idx >> 7, o = idx & 127;
    F[192 + idx] = res_pair[((size_t)h * NRES + i) * PAIRD + o];
  }
  if (t < 96) {
    int h = t >> 3, d = t & 7;
    const float* R = rot + (size_t)i * 9;
    const float* T = trans + (size_t)i * 3;
    const float* pp = res_sv + ((size_t)h * NRES + i) * 40 + 16 + d * 3;
    float p0 = pp[0] - T[0], p1 = pp[1] - T[1], p2 = pp[2] - T[2];
    float l0 = R[0] * p0 + R[3] * p1 + R[6] * p2;   // R^T
    float l1 = R[1] * p0 + R[4] * p1 + R[7] * p2;
    float l2 = R[2] * p0 + R[5] * p1 + R[8] * p2;
    F[1728 + h * 24 + d * 3 + 0] = l0;
    F[1728 + h * 24 + d * 3 + 1] = l1;
    F[1728 + h * 24 + d * 3 + 2] = l2;
    F[2016 + h * 8 + d] = sqrtf(l0 * l0 + l1 * l1 + l2 * l2 + 1e-8f);
  }
}

// ---------------- pair MLP: gelu(E@Wp1 + b1)@Wp2 + b2 (MFMA, persistent) ---
__global__ __launch_bounds__(256) void mlp_kernel(
    const float* __restrict__ attn, const float* __restrict__ sp,
    const float* __restrict__ ss, const float* __restrict__ Wp1,
    const float* __restrict__ bp1, const float* __restrict__ Wp2,
    const float* __restrict__ bp2, float* __restrict__ out)
{
  __shared__ __align__(16) unsigned short E_lds[32][72];    // [j][k], k 0..63 (36 real)
  __shared__ __align__(16) unsigned short A_lds[32][136];   // [j][o]
  int t = threadIdx.x;
  int lane = t & 63, w = t >> 6;
  int n15 = lane & 15, q = lane >> 4;
  for (int idx = t; idx < 32 * 36; idx += 256) {            // zero k = 36..71
    int j = idx / 36, k = 36 + idx % 36;
    E_lds[j][k] = 0;
  }
  s16x8 w1f[2][2], w2f[4][2];
#pragma unroll
  for (int ks = 0; ks < 2; ++ks)
#pragma unroll
    for (int nt = 0; nt < 2; ++nt) {
      int nn = (w * 2 + nt) * 16 + n15;
#pragma unroll
      for (int jj = 0; jj < 8; ++jj) {
        int k = ks * 32 + q * 8 + jj;
        w1f[ks][nt][jj] = (k < 36) ? (short)f2bf(Wp1[(size_t)k * 128 + nn]) : (short)0;
      }
    }
#pragma unroll
  for (int ks = 0; ks < 4; ++ks)
#pragma unroll
    for (int nt = 0; nt < 2; ++nt) {
      int nn = (w * 2 + nt) * 16 + n15;
#pragma unroll
      for (int jj = 0; jj < 8; ++jj) {
        int k = ks * 32 + q * 8 + jj;
        w2f[ks][nt][jj] = (short)f2bf(Wp2[(size_t)k * 128 + nn]);
      }
    }
  float b1v[2], b2v[2];
#pragma unroll
  for (int nt = 0; nt < 2; ++nt) {
    int nn = (w * 2 + nt) * 16 + n15;
    b1v[nt] = bp1[nn];
    b2v[nt] = bp2[nn];
  }
  const float* bufs[3] = {attn, sp, ss};
  for (int tile = blockIdx.x; tile < NRES * 24; tile += gridDim.x) {
    int i = tile / 24, j0 = (tile % 24) * 32;
    __syncthreads();
    {
      int j = t & 31, c0 = t >> 5;
      for (int p = 0; p < 5; ++p) {
        int c = p * 8 + c0;
        if (c < 36) {
          int hh = c % 12;
          const float* src = bufs[c / 12];
          E_lds[j][c] = f2bf(src[((size_t)hh * NRES + i) * NRES + j0 + j]);
        }
      }
    }
    __syncthreads();
    f32x4 c1[2][2];
#pragma unroll
    for (int mt = 0; mt < 2; ++mt) {
#pragma unroll
      for (int nt = 0; nt < 2; ++nt) c1[mt][nt] = (f32x4){0.f, 0.f, 0.f, 0.f};
#pragma unroll
      for (int ks = 0; ks < 2; ++ks) {
        s16x8 af = *(const s16x8*)&E_lds[mt * 16 + n15][ks * 32 + q * 8];
#pragma unroll
        for (int nt = 0; nt < 2; ++nt)
          c1[mt][nt] = __builtin_amdgcn_mfma_f32_16x16x32_bf16(af, w1f[ks][nt], c1[mt][nt], 0, 0, 0);
      }
    }
#pragma unroll
    for (int mt = 0; mt < 2; ++mt)
#pragma unroll
      for (int nt = 0; nt < 2; ++nt) {
        int o = (w * 2 + nt) * 16 + n15;
#pragma unroll
        for (int r = 0; r < 4; ++r) {
          float x = c1[mt][nt][r] + b1v[nt];
          float g = 0.5f * x * (1.f + erff(x * 0.70710678118654752f));
          A_lds[mt * 16 + q * 4 + r][o] = f2bf(g);
        }
      }
    __syncthreads();
    f32x4 c2[2][2];
#pragma unroll
    for (int mt = 0; mt < 2; ++mt) {
#pragma unroll
      for (int nt = 0; nt < 2; ++nt) c2[mt][nt] = (f32x4){0.f, 0.f, 0.f, 0.f};
#pragma unroll
      for (int ks = 0; ks < 4; ++ks) {
        s16x8 af = *(const s16x8*)&A_lds[mt * 16 + n15][ks * 32 + q * 8];
#pragma unroll
        for (int nt = 0; nt < 2; ++nt)
          c2[mt][nt] = __builtin_amdgcn_mfma_f32_16x16x32_bf16(af, w2f[ks][nt], c2[mt][nt], 0, 0, 0);
      }
    }
#pragma unroll
    for (int mt = 0; mt < 2; ++mt)
#pragma unroll
      for (int nt = 0; nt < 2; ++nt) {
        int o = (w * 2 + nt) * 16 + n15;
        int jb = j0 + mt * 16 + q * 4;
#pragma unroll
        for (int r = 0; r < 4; ++r)
          out[((size_t)i * NRES + jb + r) * PAIRD + o] = c2[mt][nt][r] + b2v[nt];
      }
  }
}

extern "C" void kernel_launch(void* const* d_in, const int* in_sizes, int n_in,
                              void* d_out, int out_size, void* d_ws, size_t ws_size,
                              hipStream_t stream) {
  const float* scalar_feats = (const float*)d_in[0];
  const float* pair  = (const float*)d_in[1];
  const float* rot   = (const float*)d_in[2];
  const float* trans = (const float*)d_in[3];
  // d_in[4] = mask (all true) - unused
  const float* Wqkv  = (const float*)d_in[5];
  const float* Wpb   = (const float*)d_in[6];
  const float* pw    = (const float*)d_in[7];
  const float* Wout  = (const float*)d_in[8];
  const float* bout  = (const float*)d_in[9];
  const float* Wp1   = (const float*)d_in[10];
  const float* bp1   = (const float*)d_in[11];
  const float* Wp2   = (const float*)d_in[12];
  const float* bp2   = (const float*)d_in[13];
  float* out = (float*)d_out;
  float* ws = (float*)d_ws;

  float* qkv = ws;                               //   884736
  float* QP  = ws + 884736;                      //   110592
  float* KP  = ws + 995328;                      //   110592
  float* VP  = ws + 1105920;                     //   221184
  unsigned short* Vt = (unsigned short*)(ws + 1327104);  // 442368 ushort
  float* Ls  = ws + 1548288;                     //  7077888
  float* Lp  = ws + 8626176;                     //  7077888
  float* Lb  = ws + 15704064;                    //  7077888
  float* res_sv   = ws + 22781952;               //   368640
  float* res_pair = ws + 23150592;               //  1179648
  float* feats    = ws + 24330240;               //  1622016  (end 25952256 = 104 MB)

  gemm_f32<<<dim3(1152 / 64, 768 / 64), 256, 0, stream>>>(
      scalar_feats, Wqkv, nullptr, qkv, 768, 1152, 384);
  points_kernel<<<768, 192, 0, stream>>>(qkv, rot, trans, QP, KP, VP);
  vt_kernel<<<576, 256, 0, stream>>>(qkv, VP, Vt);
  logits_sp_kernel<<<dim3(12, 24, 12), 256, 0, stream>>>(qkv, QP, KP, pw, Ls, Lp);
  pair_bias_kernel<<<dim3(12, 768), 256, 0, stream>>>(pair, Wpb, Lb);
  softmax_kernel<<<dim3(768, 12), 256, 0, stream>>>(Ls, Lp, Lb);
  res_sv_kernel<<<dim3(48, 12), 192, 0, stream>>>(Lb, Vt, res_sv);
  res_pair_kernel<<<768, 256, 0, stream>>>(Lb, pair, res_pair);
  feats_kernel<<<768, 256, 0, stream>>>(res_sv, res_pair, rot, trans, feats);
  gemm_f32<<<dim3(384 / 64, 768 / 64), 256, 0, stream>>>(
      feats, Wout, bout, out, 768, 384, 2112);
  mlp_kernel<<<2048, 256, 0, stream>>>(Lb, Lp, Ls, Wp1, bp1, Wp2, bp2, out + 294912);
}